// Round 5
// baseline (13519.458 us; speedup 1.0000x reference)
//
#include <hip/hip_runtime.h>
#include <math.h>

// Problem constants
#define B_ROWS 8192
#define S_LEN  512
#define H_DIM  256
#define G3     768          // 3*H
#define P_DIM  96
#define TB     32           // batch rows per block

typedef __attribute__((ext_vector_type(8))) short short8;   // 8 bf16 (4 VGPRs)
typedef __attribute__((ext_vector_type(4))) float floatx4;  // MFMA C/D frag

__device__ __forceinline__ float sigmoid_fast(float v) {
    return 1.0f / (1.0f + __expf(-v));
}
__device__ __forceinline__ float tanh_fast(float v) {
    return 1.0f - 2.0f / (__expf(2.0f * v) + 1.0f);
}
__device__ __forceinline__ unsigned short f32_bf16_rtn(float f) {
    unsigned int u = __float_as_uint(f);
    u += 0x7fffu + ((u >> 16) & 1u);   // round-to-nearest-even
    return (unsigned short)(u >> 16);
}
__device__ __forceinline__ float bf16_f32(unsigned short h) {
    return __uint_as_float(((unsigned int)h) << 16);
}

// -------- One-time weight pack: W_hh -> per-lane MFMA B-fragments (hi/lo bf16).
// B[k][n] = W_hh[n][k].  16x16x32 B-frag: lane holds B[n=lane&15][k=quad*8+j].
// Tile index = (k>>5)*48 + (j>>4); lane = (j&15) | (((k>>3)&3)<<4); short = k&7.
// Also WoT[k][p] = W_out[p][k]; also zeroes the phase-sync counter.
__global__ void pack_weights(const float* __restrict__ W_hh,
                             const float* __restrict__ W_out,
                             unsigned short* __restrict__ Bh,
                             unsigned short* __restrict__ Bl,
                             float* __restrict__ WoT,
                             unsigned int* __restrict__ ctr) {
    const int j = blockIdx.x;    // gate col 0..767
    const int k = threadIdx.x;   // h idx   0..255
    const float wv = W_hh[j * H_DIM + k];
    const unsigned short hi = f32_bf16_rtn(wv);
    const unsigned short lo = f32_bf16_rtn(wv - bf16_f32(hi));
    const int idx = (((k >> 5) * 48 + (j >> 4)) * 64 +
                     ((j & 15) | (((k >> 3) & 3) << 4))) * 8 + (k & 7);
    Bh[idx] = hi;
    Bl[idx] = lo;
    if (j < P_DIM) WoT[k * P_DIM + j] = W_out[j * H_DIM + k];
    if (j == 0 && k == 0) *ctr = 0u;   // d_ws is re-poisoned every launch
}

// LDS layout (148 KiB total):
//   [0,       65536)  A-fragments, double-buffered: buf*32768 + m(hi/lo)*16384
//                     + chunk(kc*2+mt)*1024 + g(slot)*16 + short*2
//                     where g(v) = v ^ ((v>>2)&7): reads 2-way (free), writes
//                     hit 8 distinct bank groups (rot3 had 8-way READ conflicts)
//   [65536,   69632)  xtile[2][32][16] fp32
//   [69632,  151552)  W cache: 80 tiles x 1 KiB
//                     slots 0..47  = kc=6 lo  (index g*16 + w*2 + ht)
//                     slots 48..79 = kc=5 hi, g<2 (index g*16 + w*2 + ht)
#define A_OFF   0
#define X_OFF   65536
#define W_OFF   69632
#define LDS_SZ  151552

__device__ __forceinline__ void mfma3(floatx4& c0, floatx4& c1,
                                      const short8& ah0, const short8& ah1,
                                      const short8& al0, const short8& al1,
                                      const short8& bh, const short8& bl) {
    c0 = __builtin_amdgcn_mfma_f32_16x16x32_bf16(ah0, bh, c0, 0, 0, 0);
    c1 = __builtin_amdgcn_mfma_f32_16x16x32_bf16(ah1, bh, c1, 0, 0, 0);
    c0 = __builtin_amdgcn_mfma_f32_16x16x32_bf16(al0, bh, c0, 0, 0, 0);
    c1 = __builtin_amdgcn_mfma_f32_16x16x32_bf16(al1, bh, c1, 0, 0, 0);
    c0 = __builtin_amdgcn_mfma_f32_16x16x32_bf16(ah0, bl, c0, 0, 0, 0);
    c1 = __builtin_amdgcn_mfma_f32_16x16x32_bf16(ah1, bl, c1, 0, 0, 0);
}

// Main persistent GRU kernel: split-bf16 MFMA + partial weight residency.
// grid = 256 (1 block/CU, forced by 148 KiB LDS), block = 512 (8 waves).
__global__ __launch_bounds__(512, 2)
void gru_mfma(const float* __restrict__ x,
              const float* __restrict__ W_ih,
              const float* __restrict__ b_ih,
              const float* __restrict__ b_hh,
              const unsigned short* __restrict__ Bh,
              const unsigned short* __restrict__ Bl,
              const float* __restrict__ WoT,   // [256][96]
              const float* __restrict__ b_out,
              float* __restrict__ out,
              unsigned int* __restrict__ ctr) {
    __shared__ __align__(16) char smem[LDS_SZ];

    const int tid  = threadIdx.x;
    const int w    = tid >> 6;     // wave 0..7
    const int lane = tid & 63;
    const int q    = lane >> 4;    // quad
    const int c    = lane & 15;
    const int row0 = blockIdx.x * TB;

    // Per-thread gate params; col = 256*g + 32*w + 16*ht + c
    float wih[3][2], bcc[2][2], bihn[2], bhhn[2];
#pragma unroll
    for (int g = 0; g < 3; ++g)
#pragma unroll
        for (int ht = 0; ht < 2; ++ht) {
            const int col = g * H_DIM + w * 32 + ht * 16 + c;
            wih[g][ht] = W_ih[col];
            if (g < 2) {
                bcc[g][ht] = b_ih[col] + b_hh[col];
            } else {
                bihn[ht] = b_ih[col];
                bhhn[ht] = b_hh[col];
            }
        }

    // Streamed-tile base pointers (per wave/lane), gh = g*2 + ht.
    const unsigned short* pbh[6];
    const unsigned short* pbl[6];
#pragma unroll
    for (int gh = 0; gh < 6; ++gh) {
        const size_t toff = (size_t)((gh >> 1) * 16 + w * 2 + (gh & 1)) * 512 + lane * 8;
        pbh[gh] = Bh + toff;
        pbl[gh] = Bl + toff;
    }

    union U16 { uint4 u; short8 s; };

    // Register-resident weight tiles: kc=7 hi+lo, kc=6 hi.  (72 VGPRs)
    short8 r7h[6], r7l[6], r6h[6];
#pragma unroll
    for (int gh = 0; gh < 6; ++gh) {
        U16 a, b, d;
        a.u = *(const uint4*)(pbh[gh] + 7 * 24576);
        b.u = *(const uint4*)(pbl[gh] + 7 * 24576);
        d.u = *(const uint4*)(pbh[gh] + 6 * 24576);
        r7h[gh] = a.s; r7l[gh] = b.s; r6h[gh] = d.s;
    }

    // LDS weight cache staging: 80 tiles (kc=6 lo: Bl tiles 288..335;
    // kc=5 hi g<2: Bh tiles 240..271).
    for (int i = tid; i < 80 * 64; i += 512) {
        const int slot = i >> 6, l16 = i & 63;
        const unsigned short* src = (slot < 48)
            ? (Bl + (size_t)(288 + slot) * 512 + l16 * 8)
            : (Bh + (size_t)(240 + slot - 48) * 512 + l16 * 8);
        *(uint4*)(smem + W_OFF + slot * 1024 + l16 * 16) = *(const uint4*)src;
    }

    // Zero both A-frag buffers (h0 = 0) and stage x for t=0..15.
    for (int i = tid; i < 16384; i += 512) ((int*)(smem + A_OFF))[i] = 0;
    float* xt = (float*)(smem + X_OFF);
    {
        const int r = tid >> 4, t2 = tid & 15;
        xt[r * 16 + t2] = x[(size_t)(row0 + r) * S_LEN + t2];
    }
    __syncthreads();

    // h_old in C-frag layout: element (mt,ht,reg) = h[4q+reg+16mt][32w+16ht+c]
    float h_own[2][2][4];
#pragma unroll
    for (int mt = 0; mt < 2; ++mt)
#pragma unroll
        for (int ht = 0; ht < 2; ++ht)
#pragma unroll
            for (int r = 0; r < 4; ++r) h_own[mt][ht][r] = 0.0f;

    // Swizzle g(v) = v ^ ((v>>2)&7):
    //  - reader row for lane: rl = g(lane) -> per quarter-wave each bank-group
    //    is hit exactly twice (2-way = free)
    //  - writer dest rows g(d) hit 8 distinct bank groups per store instr
    const int rl16 = (lane ^ ((lane >> 2) & 7)) << 4;
    const int gxor = q + 4 * (c >> 3);       // == (d>>2)&7, thread-constant

    for (int t = 0; t < S_LEN; ++t) {
        const int cur = t & 1, nxt = cur ^ 1;
        const char* Ah = smem + A_OFF + cur * 32768;
        const char* Al = Ah + 16384;

        // x for my 8 rows (LDS broadcast)
        float xr[2][4];
#pragma unroll
        for (int mt = 0; mt < 2; ++mt)
#pragma unroll
            for (int r = 0; r < 4; ++r)
                xr[mt][r] = xt[(((t >> 4) & 1) * 32 + q * 4 + r + 16 * mt) * 16 + (t & 15)];

        // C frags [gate][mt][ht]; fold x-side pre-activation + bias into init.
        floatx4 acc[3][2][2];
#pragma unroll
        for (int mt = 0; mt < 2; ++mt)
#pragma unroll
            for (int ht = 0; ht < 2; ++ht)
#pragma unroll
                for (int r = 0; r < 4; ++r) {
                    acc[0][mt][ht][r] = fmaf(xr[mt][r], wih[0][ht], bcc[0][ht]);
                    acc[1][mt][ht][r] = fmaf(xr[mt][r], wih[1][ht], bcc[1][ht]);
                    acc[2][mt][ht][r] = bhhn[ht];
                }

        // ---- kc = 0..4: fully streamed from L2.  Fully unrolled so the
        // compiler can hoist/pipeline B loads across the MFMA blocks. ----
#pragma unroll
        for (int kc = 0; kc < 5; ++kc) {
            short8 ah[2], al[2];
#pragma unroll
            for (int mt = 0; mt < 2; ++mt) {
                ah[mt] = *(const short8*)(Ah + (kc * 2 + mt) * 1024 + rl16);
                al[mt] = *(const short8*)(Al + (kc * 2 + mt) * 1024 + rl16);
            }
#pragma unroll
            for (int gh = 0; gh < 6; ++gh) {
                U16 bh, bl;
                bh.u = *(const uint4*)(pbh[gh] + (size_t)kc * 24576);
                bl.u = *(const uint4*)(pbl[gh] + (size_t)kc * 24576);
                mfma3(acc[gh >> 1][0][gh & 1], acc[gh >> 1][1][gh & 1],
                      ah[0], ah[1], al[0], al[1], bh.s, bl.s);
            }
        }

        // ---- kc = 5: hi g<2 from LDS, hi g=2 + all lo streamed ----
        {
            short8 ah[2], al[2];
#pragma unroll
            for (int mt = 0; mt < 2; ++mt) {
                ah[mt] = *(const short8*)(Ah + (10 + mt) * 1024 + rl16);
                al[mt] = *(const short8*)(Al + (10 + mt) * 1024 + rl16);
            }
#pragma unroll
            for (int gh = 0; gh < 6; ++gh) {
                U16 bh, bl;
                if (gh < 4) {
                    const int slot = 48 + (gh >> 1) * 16 + w * 2 + (gh & 1);
                    bh.s = *(const short8*)(smem + W_OFF + slot * 1024 + lane * 16);
                } else {
                    bh.u = *(const uint4*)(pbh[gh] + (size_t)5 * 24576);
                }
                bl.u = *(const uint4*)(pbl[gh] + (size_t)5 * 24576);
                mfma3(acc[gh >> 1][0][gh & 1], acc[gh >> 1][1][gh & 1],
                      ah[0], ah[1], al[0], al[1], bh.s, bl.s);
            }
        }

        // ---- kc = 6: hi from regs, lo from LDS ----
        {
            short8 ah[2], al[2];
#pragma unroll
            for (int mt = 0; mt < 2; ++mt) {
                ah[mt] = *(const short8*)(Ah + (12 + mt) * 1024 + rl16);
                al[mt] = *(const short8*)(Al + (12 + mt) * 1024 + rl16);
            }
#pragma unroll
            for (int gh = 0; gh < 6; ++gh) {
                const int slot = (gh >> 1) * 16 + w * 2 + (gh & 1);
                short8 bl = *(const short8*)(smem + W_OFF + slot * 1024 + lane * 16);
                mfma3(acc[gh >> 1][0][gh & 1], acc[gh >> 1][1][gh & 1],
                      ah[0], ah[1], al[0], al[1], r6h[gh], bl);
            }
        }

        // ---- kc = 7: fully register-resident ----
        {
            short8 ah[2], al[2];
#pragma unroll
            for (int mt = 0; mt < 2; ++mt) {
                ah[mt] = *(const short8*)(Ah + (14 + mt) * 1024 + rl16);
                al[mt] = *(const short8*)(Al + (14 + mt) * 1024 + rl16);
            }
#pragma unroll
            for (int gh = 0; gh < 6; ++gh)
                mfma3(acc[gh >> 1][0][gh & 1], acc[gh >> 1][1][gh & 1],
                      ah[0], ah[1], al[0], al[1], r7h[gh], r7l[gh]);
        }

        // Gates + h update (in-register); scatter next A-frags (g-swizzled).
        char* Anx = smem + A_OFF + nxt * 32768;
#pragma unroll
        for (int mt = 0; mt < 2; ++mt) {
            char* chh = Anx + (w * 2 + mt) * 1024;          // hi chunk (kc=w)
            char* cll = chh + 16384;                        // lo chunk
#pragma unroll
            for (int ht = 0; ht < 2; ++ht)
#pragma unroll
                for (int r = 0; r < 4; ++r) {
                    const float rr  = sigmoid_fast(acc[0][mt][ht][r]);
                    const float zz  = sigmoid_fast(acc[1][mt][ht][r]);
                    const float inn = fmaf(xr[mt][r], wih[2][ht], bihn[ht]);
                    const float nn  = tanh_fast(fmaf(rr, acc[2][mt][ht][r], inn));
                    const float hv  = (1.0f - zz) * nn + zz * h_own[mt][ht][r];
                    h_own[mt][ht][r] = hv;
                    const unsigned short hi = f32_bf16_rtn(hv);
                    // lo truncated (error 2^-17-relative, invisible vs 2^-11)
                    const unsigned short lo =
                        (unsigned short)(__float_as_uint(hv - bf16_f32(hi)) >> 16);
                    const int d   = (q * 4 + r) | ((2 * ht + (c >> 3)) << 4);
                    const int off = ((d ^ gxor) << 4) + ((c & 7) << 1);
                    *(unsigned short*)(chh + off) = hi;
                    *(unsigned short*)(cll + off) = lo;
                }
        }

        // Re-stage x for the next 16 steps (into the idle x buffer).
        const bool tick = ((t & 15) == 15) && (t != S_LEN - 1);
        if (tick) {
            const int r = tid >> 4, t2 = tid & 15;
            xt[((((t + 1) >> 4) & 1) * 32 + r) * 16 + t2] =
                x[(size_t)(row0 + r) * S_LEN + (t + 1) + t2];
        }
        __syncthreads();   // single barrier: next A-frags + x tile visible

        // Phase-alignment heartbeat every 16 steps: keeps all 256 blocks'
        // weight streams in phase so the per-XCD L2 working set stays hot.
        // Pure timing hint — bounded spin, no data dependency, no fences.
        if (tick) {
            if (tid == 0) {
                const unsigned int tgt = 256u * (unsigned)((t >> 4) + 1);
                atomicAdd(ctr, 1u);
                for (int spin = 0; spin < (1 << 17); ++spin) {
                    if (__hip_atomic_load(ctr, __ATOMIC_RELAXED,
                                          __HIP_MEMORY_SCOPE_AGENT) >= tgt) break;
                    __builtin_amdgcn_s_sleep(4);
                }
            }
            __syncthreads();
        }
    }

    // -------- Epilogue: dump final h (fp32, from registers) and project.
    float* hfin = (float*)(smem);   // reuse A region: [32][256]
#pragma unroll
    for (int mt = 0; mt < 2; ++mt)
#pragma unroll
        for (int ht = 0; ht < 2; ++ht)
#pragma unroll
            for (int r = 0; r < 4; ++r) {
                const int m = q * 4 + r + 16 * mt;
                const int k = w * 32 + ht * 16 + c;
                hfin[m * H_DIM + k] = h_own[mt][ht][r];
            }
    __syncthreads();

    if (tid < 256) {
        const int cid   = tid & 63;
        const int rid   = tid >> 6;
        const int myrow = rid * 8;
        const int pA    = cid;
        const int pB    = 64 + cid;
        const bool hasB = (cid < 32);
        float accA[8], accB[8];
#pragma unroll
        for (int rr = 0; rr < 8; ++rr) { accA[rr] = 0.0f; accB[rr] = 0.0f; }

        for (int k = 0; k < H_DIM; k += 4) {
            float4 hv[8];
#pragma unroll
            for (int rr = 0; rr < 8; ++rr)
                hv[rr] = *(const float4*)&hfin[(myrow + rr) * H_DIM + k];
            float wA[4], wB[4];
#pragma unroll
            for (int kk = 0; kk < 4; ++kk) {
                wA[kk] = WoT[(size_t)(k + kk) * P_DIM + pA];
                wB[kk] = hasB ? WoT[(size_t)(k + kk) * P_DIM + pB] : 0.0f;
            }
#pragma unroll
            for (int kk = 0; kk < 4; ++kk)
#pragma unroll
                for (int rr = 0; rr < 8; ++rr) {
                    const float hvv = (&hv[rr].x)[kk];
                    accA[rr] = fmaf(hvv, wA[kk], accA[rr]);
                    accB[rr] = fmaf(hvv, wB[kk], accB[rr]);
                }
        }
        const float boA = b_out[pA];
        const float boB = hasB ? b_out[pB] : 0.0f;
#pragma unroll
        for (int rr = 0; rr < 8; ++rr) {
            const size_t orow = (size_t)(row0 + myrow + rr) * P_DIM;
            out[orow + pA] = accA[rr] + boA;
            if (hasB) out[orow + pB] = accB[rr] + boB;
        }
    }
}

// -------- fp32 fallback — used only if ws_size is too small.
__global__ __launch_bounds__(256, 1)
void gru_fallback(const float* __restrict__ x,
                  const float* __restrict__ W_ih,
                  const float* __restrict__ Whh,
                  const float* __restrict__ b_ih,
                  const float* __restrict__ b_hh,
                  const float* __restrict__ Wout,
                  const float* __restrict__ b_out,
                  float* __restrict__ out) {
    __shared__ float hbuf[2][TB][H_DIM];

    const int tid   = threadIdx.x;
    const int cid   = tid & 63;
    const int rid   = tid >> 6;
    const int row0  = blockIdx.x * TB;
    const int myrow = rid * 8;
    const int c0    = cid * 4;

    float wih[3][4], bc[2][4], bihn[4], bhhn[4];
#pragma unroll
    for (int cc = 0; cc < 4; ++cc) {
        const int j = c0 + cc;
        wih[0][cc] = W_ih[j];
        wih[1][cc] = W_ih[H_DIM + j];
        wih[2][cc] = W_ih[2 * H_DIM + j];
        bc[0][cc]  = b_ih[j] + b_hh[j];
        bc[1][cc]  = b_ih[H_DIM + j] + b_hh[H_DIM + j];
        bihn[cc]   = b_ih[2 * H_DIM + j];
        bhhn[cc]   = b_hh[2 * H_DIM + j];
    }
    for (int i = tid; i < TB * H_DIM; i += 256) (&hbuf[0][0][0])[i] = 0.0f;
    float h_own[8][4];
#pragma unroll
    for (int rr = 0; rr < 8; ++rr)
#pragma unroll
        for (int cc = 0; cc < 4; ++cc) h_own[rr][cc] = 0.0f;
    __syncthreads();

    int p = 0;
    for (int t = 0; t < S_LEN; ++t) {
        float xv[8];
#pragma unroll
        for (int rr = 0; rr < 8; ++rr)
            xv[rr] = x[(size_t)(row0 + myrow + rr) * S_LEN + t];

        float acc[3][8][4];
#pragma unroll
        for (int rr = 0; rr < 8; ++rr)
#pragma unroll
            for (int cc = 0; cc < 4; ++cc) {
                acc[0][rr][cc] = fmaf(xv[rr], wih[0][cc], bc[0][cc]);
                acc[1][rr][cc] = fmaf(xv[rr], wih[1][cc], bc[1][cc]);
                acc[2][rr][cc] = bhhn[cc];
            }
        const float* hb = &hbuf[p][0][0];
        for (int k = 0; k < H_DIM; k += 4) {
            float4 hv[8];
#pragma unroll
            for (int rr = 0; rr < 8; ++rr)
                hv[rr] = *(const float4*)(hb + (myrow + rr) * H_DIM + k);
#pragma unroll
            for (int g = 0; g < 3; ++g)
#pragma unroll
                for (int kk = 0; kk < 4; ++kk) {
                    float wrow[4];
#pragma unroll
                    for (int cc = 0; cc < 4; ++cc)
                        wrow[cc] = Whh[(size_t)(g * H_DIM + c0 + cc) * H_DIM + k + kk];
#pragma unroll
                    for (int rr = 0; rr < 8; ++rr) {
                        const float hvv = (&hv[rr].x)[kk];
#pragma unroll
                        for (int cc = 0; cc < 4; ++cc)
                            acc[g][rr][cc] = fmaf(hvv, wrow[cc], acc[g][rr][cc]);
                    }
                }
        }
#pragma unroll
        for (int rr = 0; rr < 8; ++rr) {
            float4 hnew;
#pragma unroll
            for (int cc = 0; cc < 4; ++cc) {
                const float r_  = sigmoid_fast(acc[0][rr][cc]);
                const float z_  = sigmoid_fast(acc[1][rr][cc]);
                const float i_n = fmaf(xv[rr], wih[2][cc], bihn[cc]);
                const float n_  = tanh_fast(fmaf(r_, acc[2][rr][cc], i_n));
                const float hv2 = (1.0f - z_) * n_ + z_ * h_own[rr][cc];
                h_own[rr][cc] = hv2;
                (&hnew.x)[cc] = hv2;
            }
            *(float4*)&hbuf[1 - p][myrow + rr][c0] = hnew;
        }
        __syncthreads();
        p ^= 1;
    }

    const int  pA   = cid;
    const int  pB   = 64 + cid;
    const bool hasB = (cid < 32);
    float accA[8], accB[8];
#pragma unroll
    for (int rr = 0; rr < 8; ++rr) { accA[rr] = 0.0f; accB[rr] = 0.0f; }
    for (int k = 0; k < H_DIM; k += 4) {
        float4 hv[8];
#pragma unroll
        for (int rr = 0; rr < 8; ++rr)
            hv[rr] = *(const float4*)&hbuf[p][myrow + rr][k];
        float wA[4], wB[4];
#pragma unroll
        for (int kk = 0; kk < 4; ++kk) {
            wA[kk] = Wout[(size_t)pA * H_DIM + k + kk];
            wB[kk] = hasB ? Wout[(size_t)pB * H_DIM + k + kk] : 0.0f;
        }
#pragma unroll
        for (int kk = 0; kk < 4; ++kk)
#pragma unroll
            for (int rr = 0; rr < 8; ++rr) {
                const float hvv = (&hv[rr].x)[kk];
                accA[rr] = fmaf(hvv, wA[kk], accA[rr]);
                accB[rr] = fmaf(hvv, wB[kk], accB[rr]);
            }
    }
    const float boA = b_out[pA];
    const float boB = hasB ? b_out[pB] : 0.0f;
#pragma unroll
    for (int rr = 0; rr < 8; ++rr) {
        const size_t orow = (size_t)(row0 + myrow + rr) * P_DIM;
        out[orow + pA] = accA[rr] + boA;
        if (hasB) out[orow + pB] = accB[rr] + boB;
    }
}

extern "C" void kernel_launch(void* const* d_in, const int* in_sizes, int n_in,
                              void* d_out, int out_size, void* d_ws, size_t ws_size,
                              hipStream_t stream) {
    const float* x     = (const float*)d_in[0];
    const float* W_ih  = (const float*)d_in[1];
    const float* W_hh  = (const float*)d_in[2];
    const float* b_ih  = (const float*)d_in[3];
    const float* b_hh  = (const float*)d_in[4];
    const float* W_out = (const float*)d_in[5];
    const float* b_out = (const float*)d_in[6];
    float* out = (float*)d_out;

    const size_t bpack_elems = 8 * 48 * 64 * 8;          // 196608 bf16 per matrix
    const size_t wot_elems   = (size_t)H_DIM * P_DIM;    // 24576 fp32
    const size_t ctr_off = bpack_elems * 2 * sizeof(unsigned short) * 2 +
                           wot_elems * sizeof(float);    // 1671168 B (16-aligned)
    const size_t need = ctr_off + sizeof(unsigned int);

    if (ws_size >= need) {
        unsigned short* Bh = (unsigned short*)d_ws;
        unsigned short* Bl = Bh + bpack_elems * 2;
        float* WoT = (float*)(Bl + bpack_elems * 2);
        unsigned int* ctr = (unsigned int*)((char*)d_ws + ctr_off);
        pack_weights<<<G3, H_DIM, 0, stream>>>(W_hh, W_out, Bh, Bl, WoT, ctr);
        gru_mfma<<<B_ROWS / TB, 512, 0, stream>>>(x, W_ih, b_ih, b_hh,
                                                  Bh, Bl, WoT, b_out, out, ctr);
    } else {
        gru_fallback<<<B_ROWS / TB, 256, 0, stream>>>(x, W_ih, W_hh, b_ih, b_hh,
                                                      W_out, b_out, out);
    }
}

// Round 6
// 8575.755 us; speedup vs baseline: 1.5765x; 1.5765x over previous
//
#include <hip/hip_runtime.h>
#include <math.h>

// Problem constants
#define B_ROWS 8192
#define S_LEN  512
#define H_DIM  256
#define G3     768          // 3*H
#define P_DIM  96
#define TB     32           // batch rows per block

typedef __attribute__((ext_vector_type(8))) short short8;   // 8 bf16 (4 VGPRs)
typedef __attribute__((ext_vector_type(4))) float floatx4;  // MFMA C/D frag

__device__ __forceinline__ float sigmoid_fast(float v) {
    return 1.0f / (1.0f + __expf(-v));
}
__device__ __forceinline__ float tanh_fast(float v) {
    return 1.0f - 2.0f / (__expf(2.0f * v) + 1.0f);
}
__device__ __forceinline__ unsigned short f32_bf16_rtn(float f) {
    unsigned int u = __float_as_uint(f);
    u += 0x7fffu + ((u >> 16) & 1u);   // round-to-nearest-even
    return (unsigned short)(u >> 16);
}
__device__ __forceinline__ float bf16_f32(unsigned short h) {
    return __uint_as_float(((unsigned int)h) << 16);
}

// -------- One-time weight pack: W_hh -> per-lane MFMA B-fragments (hi/lo bf16).
// B[k][n] = W_hh[n][k].  16x16x32 B-frag: lane holds B[n=lane&15][k=quad*8+j].
// Tile index = (k>>5)*48 + (j>>4); lane = (j&15) | (((k>>3)&3)<<4); short = k&7.
// Also WoT[k][p] = W_out[p][k]; also zeroes the phase-sync counter.
__global__ void pack_weights(const float* __restrict__ W_hh,
                             const float* __restrict__ W_out,
                             unsigned short* __restrict__ Bh,
                             unsigned short* __restrict__ Bl,
                             float* __restrict__ WoT,
                             unsigned int* __restrict__ ctr) {
    const int j = blockIdx.x;    // gate col 0..767
    const int k = threadIdx.x;   // h idx   0..255
    const float wv = W_hh[j * H_DIM + k];
    const unsigned short hi = f32_bf16_rtn(wv);
    const unsigned short lo = f32_bf16_rtn(wv - bf16_f32(hi));
    const int idx = (((k >> 5) * 48 + (j >> 4)) * 64 +
                     ((j & 15) | (((k >> 3) & 3) << 4))) * 8 + (k & 7);
    Bh[idx] = hi;
    Bl[idx] = lo;
    if (j < P_DIM) WoT[k * P_DIM + j] = W_out[j * H_DIM + k];
    if (j == 0 && k == 0) *ctr = 0u;   // d_ws is re-poisoned every launch
}

// LDS layout (~148 KiB):
//   [0,       65536)  A-fragments, double-buffered: buf*32768 + (hi/lo)*16384
//                     + chunk(kc*2+mt)*1024 + slot*16 + short*2, slot = g(row),
//                     g(v) = v ^ ((v>>2)&7)  (reads 2-way=free, writes 8 groups)
//   [65536,   69888)  xtile[2][32][17] fp32 (stride 17 kills 4-way bcast conflicts)
//   [69888,  151808)  W cache: 80 tiles x 1 KiB
//                     slots 0..47  = kc=6 lo  (index g*16 + w*2 + ht)
//                     slots 48..79 = kc=5 hi, g<2 (index g*16 + w*2 + ht)
#define A_OFF   0
#define X_OFF   65536
#define W_OFF   69888
#define LDS_SZ  151808
#define XSTR    17

union U16 { uint4 u; short8 s; };

__device__ __forceinline__ void mfma3(floatx4& c0, floatx4& c1,
                                      const short8& ah0, const short8& ah1,
                                      const short8& al0, const short8& al1,
                                      const short8& bh, const short8& bl) {
    c0 = __builtin_amdgcn_mfma_f32_16x16x32_bf16(ah0, bh, c0, 0, 0, 0);
    c1 = __builtin_amdgcn_mfma_f32_16x16x32_bf16(ah1, bh, c1, 0, 0, 0);
    c0 = __builtin_amdgcn_mfma_f32_16x16x32_bf16(al0, bh, c0, 0, 0, 0);
    c1 = __builtin_amdgcn_mfma_f32_16x16x32_bf16(al1, bh, c1, 0, 0, 0);
    c0 = __builtin_amdgcn_mfma_f32_16x16x32_bf16(ah0, bl, c0, 0, 0, 0);
    c1 = __builtin_amdgcn_mfma_f32_16x16x32_bf16(ah1, bl, c1, 0, 0, 0);
}

// Load the 6 streamed B-tile pairs of chunk kc_ (SGPR-base + 32-bit voffset form).
#define LOAD_B(dh, dl, kc_) {                                        \
    const size_t kb = (size_t)(kc_) * 49152;                         \
    _Pragma("unroll") for (int gh = 0; gh < 6; ++gh) {               \
        dh[gh].u = *(const uint4*)(BhB + kb + boff[gh]);             \
        dl[gh].u = *(const uint4*)(BlB + kb + boff[gh]);             \
    } }

// A-frag loads + 36 MFMAs for chunk kc_ against register B sets bh_/bl_.
#define MFMA_KC(kc_, bh_, bl_) {                                     \
    const int cb = ((kc_) * 2) << 10;                                \
    short8 ah0 = *(const short8*)(Ah + cb + rl16);                   \
    short8 ah1 = *(const short8*)(Ah + cb + 1024 + rl16);            \
    short8 al0 = *(const short8*)(Al + cb + rl16);                   \
    short8 al1 = *(const short8*)(Al + cb + 1024 + rl16);            \
    _Pragma("unroll") for (int gh = 0; gh < 6; ++gh)                 \
        mfma3(acc[gh >> 1][0][gh & 1], acc[gh >> 1][1][gh & 1],      \
              ah0, ah1, al0, al1, bh_[gh].s, bl_[gh].s);             \
    }

// Main persistent GRU kernel: split-bf16 MFMA + partial weight residency
// + depth-1 bounded software pipeline on the streamed chunks.
// grid = 256 (1 block/CU, forced by LDS), block = 512 (8 waves, 2/SIMD).
__global__ __launch_bounds__(512, 2)
void gru_mfma(const float* __restrict__ x,
              const float* __restrict__ W_ih,
              const float* __restrict__ b_ih,
              const float* __restrict__ b_hh,
              const unsigned short* __restrict__ Bh,
              const unsigned short* __restrict__ Bl,
              const float* __restrict__ WoT,   // [256][96]
              const float* __restrict__ b_out,
              float* __restrict__ out,
              unsigned int* __restrict__ ctr) {
    __shared__ __align__(16) char smem[LDS_SZ];

    const int tid  = threadIdx.x;
    const int w    = tid >> 6;     // wave 0..7
    const int lane = tid & 63;
    const int q    = lane >> 4;    // quad
    const int c    = lane & 15;
    const int row0 = blockIdx.x * TB;

    const char* BhB = (const char*)Bh;
    const char* BlB = (const char*)Bl;

    // Per-thread gate params; col = 256*g + 32*w + 16*ht + c
    float wih[3][2], bcc[2][2], bihn[2], bhhn[2];
#pragma unroll
    for (int g = 0; g < 3; ++g)
#pragma unroll
        for (int ht = 0; ht < 2; ++ht) {
            const int col = g * H_DIM + w * 32 + ht * 16 + c;
            wih[g][ht] = W_ih[col];
            if (g < 2) {
                bcc[g][ht] = b_ih[col] + b_hh[col];
            } else {
                bihn[ht] = b_ih[col];
                bhhn[ht] = b_hh[col];
            }
        }

    // 32-bit per-lane tile offsets (gh = g*2 + ht); kc adds kc*49152.
    unsigned int boff[6];
#pragma unroll
    for (int gh = 0; gh < 6; ++gh)
        boff[gh] = (unsigned)((((gh >> 1) * 16 + w * 2 + (gh & 1)) << 10) + (lane << 4));

    // Register-resident weight tiles: kc=7 hi+lo, kc=6 hi.  (72 VGPRs)
    short8 r7h[6], r7l[6], r6h[6];
#pragma unroll
    for (int gh = 0; gh < 6; ++gh) {
        U16 a, b, d;
        a.u = *(const uint4*)(BhB + (size_t)7 * 49152 + boff[gh]);
        b.u = *(const uint4*)(BlB + (size_t)7 * 49152 + boff[gh]);
        d.u = *(const uint4*)(BhB + (size_t)6 * 49152 + boff[gh]);
        r7h[gh] = a.s; r7l[gh] = b.s; r6h[gh] = d.s;
    }

    // LDS weight cache staging: 80 tiles (kc=6 lo: Bl tiles 288..335;
    // kc=5 hi g<2: Bh tiles 240..271).
    for (int i = tid; i < 80 * 64; i += 512) {
        const int slot = i >> 6, l16 = i & 63;
        const unsigned short* src = (slot < 48)
            ? (Bl + (size_t)(288 + slot) * 512 + l16 * 8)
            : (Bh + (size_t)(240 + slot - 48) * 512 + l16 * 8);
        *(uint4*)(smem + W_OFF + slot * 1024 + l16 * 16) = *(const uint4*)src;
    }

    // Zero both A-frag buffers (h0 = 0) and stage x for t=0..15.
    for (int i = tid; i < 16384; i += 512) ((int*)(smem + A_OFF))[i] = 0;
    float* xt = (float*)(smem + X_OFF);
    {
        const int r = tid >> 4, t2 = tid & 15;
        xt[r * XSTR + t2] = x[(size_t)(row0 + r) * S_LEN + t2];
    }
    __syncthreads();

    // h_old in C-frag layout: element (mt,ht,reg) = h[4q+reg+16mt][32w+16ht+c]
    float h_own[2][2][4];
#pragma unroll
    for (int mt = 0; mt < 2; ++mt)
#pragma unroll
        for (int ht = 0; ht < 2; ++ht)
#pragma unroll
            for (int r = 0; r < 4; ++r) h_own[mt][ht][r] = 0.0f;

    // Swizzle g(v) = v ^ ((v>>2)&7): reads 2-way (free); writer dest rows
    // hit 8 distinct bank groups per store.
    const int rl16 = (lane ^ ((lane >> 2) & 7)) << 4;
    const int gxor = q + 4 * (c >> 3);       // == (d>>2)&7, thread-constant

    for (int t = 0; t < S_LEN; ++t) {
        const int cur = t & 1, nxt = cur ^ 1;
        const char* Ah = smem + A_OFF + cur * 32768;
        const char* Al = Ah + 16384;

        // x for my 8 rows (LDS broadcast, conflict-free via XSTR=17)
        float xr[2][4];
#pragma unroll
        for (int mt = 0; mt < 2; ++mt)
#pragma unroll
            for (int r = 0; r < 4; ++r)
                xr[mt][r] = xt[(((t >> 4) & 1) * 32 + q * 4 + r + 16 * mt) * XSTR + (t & 15)];

        // C frags [gate][mt][ht]; fold x-side pre-activation + bias into init.
        floatx4 acc[3][2][2];
#pragma unroll
        for (int mt = 0; mt < 2; ++mt)
#pragma unroll
            for (int ht = 0; ht < 2; ++ht)
#pragma unroll
                for (int r = 0; r < 4; ++r) {
                    acc[0][mt][ht][r] = fmaf(xr[mt][r], wih[0][ht], bcc[0][ht]);
                    acc[1][mt][ht][r] = fmaf(xr[mt][r], wih[1][ht], bcc[1][ht]);
                    acc[2][mt][ht][r] = bhhn[ht];
                }

        // ---- kc = 0..4 streamed, depth-1 ping-pong pipeline (bounded:
        // 24 uint4 in flight; round-5's full unroll wanted ~60 -> spills) ----
        U16 eh[6], el[6], oh[6], ol[6];
        LOAD_B(eh, el, 0)
#pragma unroll 1
        for (int kc2 = 0; kc2 < 2; ++kc2) {
            const int k0 = kc2 << 1;
            LOAD_B(oh, ol, k0 + 1)        // prefetch odd chunk
            MFMA_KC(k0, eh, el)           // consume even
            LOAD_B(eh, el, k0 + 2)        // prefetch next even (2,4)
            MFMA_KC(k0 + 1, oh, ol)       // consume odd
        }
        // prefetch kc=5's streamed parts (hi gh>=4, lo all) before kc=4 MFMAs
        {
            const size_t kb = (size_t)5 * 49152;
            oh[4].u = *(const uint4*)(BhB + kb + boff[4]);
            oh[5].u = *(const uint4*)(BhB + kb + boff[5]);
#pragma unroll
            for (int gh = 0; gh < 6; ++gh)
                ol[gh].u = *(const uint4*)(BlB + kb + boff[gh]);
        }
        MFMA_KC(4, eh, el)

        // ---- kc = 5: hi g<2 from LDS cache, hi g=2 + all lo prefetched ----
        {
            const int cb = 10 << 10;
            short8 ah0 = *(const short8*)(Ah + cb + rl16);
            short8 ah1 = *(const short8*)(Ah + cb + 1024 + rl16);
            short8 al0 = *(const short8*)(Al + cb + rl16);
            short8 al1 = *(const short8*)(Al + cb + 1024 + rl16);
#pragma unroll
            for (int gh = 0; gh < 6; ++gh) {
                short8 bh;
                if (gh < 4) {
                    const int slot = 48 + (gh >> 1) * 16 + w * 2 + (gh & 1);
                    bh = *(const short8*)(smem + W_OFF + slot * 1024 + lane * 16);
                } else {
                    bh = oh[gh].s;
                }
                mfma3(acc[gh >> 1][0][gh & 1], acc[gh >> 1][1][gh & 1],
                      ah0, ah1, al0, al1, bh, ol[gh].s);
            }
        }

        // ---- kc = 6: hi from regs, lo from LDS cache ----
        {
            const int cb = 12 << 10;
            short8 ah0 = *(const short8*)(Ah + cb + rl16);
            short8 ah1 = *(const short8*)(Ah + cb + 1024 + rl16);
            short8 al0 = *(const short8*)(Al + cb + rl16);
            short8 al1 = *(const short8*)(Al + cb + 1024 + rl16);
#pragma unroll
            for (int gh = 0; gh < 6; ++gh) {
                const int slot = (gh >> 1) * 16 + w * 2 + (gh & 1);
                short8 bl = *(const short8*)(smem + W_OFF + slot * 1024 + lane * 16);
                mfma3(acc[gh >> 1][0][gh & 1], acc[gh >> 1][1][gh & 1],
                      ah0, ah1, al0, al1, r6h[gh], bl);
            }
        }

        // ---- kc = 7: fully register-resident ----
        {
            const int cb = 14 << 10;
            short8 ah0 = *(const short8*)(Ah + cb + rl16);
            short8 ah1 = *(const short8*)(Ah + cb + 1024 + rl16);
            short8 al0 = *(const short8*)(Al + cb + rl16);
            short8 al1 = *(const short8*)(Al + cb + 1024 + rl16);
#pragma unroll
            for (int gh = 0; gh < 6; ++gh)
                mfma3(acc[gh >> 1][0][gh & 1], acc[gh >> 1][1][gh & 1],
                      ah0, ah1, al0, al1, r7h[gh], r7l[gh]);
        }

        // Gates + h update (in-register); scatter next A-frags (g-swizzled).
        char* Anx = smem + A_OFF + nxt * 32768;
#pragma unroll
        for (int mt = 0; mt < 2; ++mt) {
            char* chh = Anx + (w * 2 + mt) * 1024;          // hi chunk (kc=w)
            char* cll = chh + 16384;                        // lo chunk
#pragma unroll
            for (int ht = 0; ht < 2; ++ht)
#pragma unroll
                for (int r = 0; r < 4; ++r) {
                    const float rr  = sigmoid_fast(acc[0][mt][ht][r]);
                    const float zz  = sigmoid_fast(acc[1][mt][ht][r]);
                    const float inn = fmaf(xr[mt][r], wih[2][ht], bihn[ht]);
                    const float nn  = tanh_fast(fmaf(rr, acc[2][mt][ht][r], inn));
                    const float hv  = (1.0f - zz) * nn + zz * h_own[mt][ht][r];
                    h_own[mt][ht][r] = hv;
                    const unsigned short hi = f32_bf16_rtn(hv);
                    // lo truncated (error 2^-17-relative, invisible vs 2^-11)
                    const unsigned short lo =
                        (unsigned short)(__float_as_uint(hv - bf16_f32(hi)) >> 16);
                    const int d   = (q * 4 + r) | ((2 * ht + (c >> 3)) << 4);
                    const int off = ((d ^ gxor) << 4) + ((c & 7) << 1);
                    *(unsigned short*)(chh + off) = hi;
                    *(unsigned short*)(cll + off) = lo;
                }
        }

        // Re-stage x for the next 16 steps (into the idle x buffer).
        const bool tick = ((t & 15) == 15) && (t != S_LEN - 1);
        if (tick) {
            const int r = tid >> 4, t2 = tid & 15;
            xt[((((t + 1) >> 4) & 1) * 32 + r) * XSTR + t2] =
                x[(size_t)(row0 + r) * S_LEN + (t + 1) + t2];
        }
        __syncthreads();   // single barrier: next A-frags + x tile visible

        // Phase-alignment heartbeat every 16 steps: keeps all 256 blocks'
        // weight streams in phase so the per-XCD L2 working set stays hot.
        // Pure timing hint — bounded spin, no data dependency, no fences.
        if (tick) {
            if (tid == 0) {
                const unsigned int tgt = 256u * (unsigned)((t >> 4) + 1);
                atomicAdd(ctr, 1u);
                for (int spin = 0; spin < (1 << 14); ++spin) {
                    if (__hip_atomic_load(ctr, __ATOMIC_RELAXED,
                                          __HIP_MEMORY_SCOPE_AGENT) >= tgt) break;
                    __builtin_amdgcn_s_sleep(4);
                }
            }
            __syncthreads();
        }
    }

    // -------- Epilogue: dump final h (fp32, from registers) and project.
    float* hfin = (float*)(smem);   // reuse A region: [32][256]
#pragma unroll
    for (int mt = 0; mt < 2; ++mt)
#pragma unroll
        for (int ht = 0; ht < 2; ++ht)
#pragma unroll
            for (int r = 0; r < 4; ++r) {
                const int m = q * 4 + r + 16 * mt;
                const int k = w * 32 + ht * 16 + c;
                hfin[m * H_DIM + k] = h_own[mt][ht][r];
            }
    __syncthreads();

    if (tid < 256) {
        const int cid   = tid & 63;
        const int rid   = tid >> 6;
        const int myrow = rid * 8;
        const int pA    = cid;
        const int pB    = 64 + cid;
        const bool hasB = (cid < 32);
        float accA[8], accB[8];
#pragma unroll
        for (int rr = 0; rr < 8; ++rr) { accA[rr] = 0.0f; accB[rr] = 0.0f; }

        for (int k = 0; k < H_DIM; k += 4) {
            float4 hv[8];
#pragma unroll
            for (int rr = 0; rr < 8; ++rr)
                hv[rr] = *(const float4*)&hfin[(myrow + rr) * H_DIM + k];
            float wA[4], wB[4];
#pragma unroll
            for (int kk = 0; kk < 4; ++kk) {
                wA[kk] = WoT[(size_t)(k + kk) * P_DIM + pA];
                wB[kk] = hasB ? WoT[(size_t)(k + kk) * P_DIM + pB] : 0.0f;
            }
#pragma unroll
            for (int kk = 0; kk < 4; ++kk)
#pragma unroll
                for (int rr = 0; rr < 8; ++rr) {
                    const float hvv = (&hv[rr].x)[kk];
                    accA[rr] = fmaf(hvv, wA[kk], accA[rr]);
                    accB[rr] = fmaf(hvv, wB[kk], accB[rr]);
                }
        }
        const float boA = b_out[pA];
        const float boB = hasB ? b_out[pB] : 0.0f;
#pragma unroll
        for (int rr = 0; rr < 8; ++rr) {
            const size_t orow = (size_t)(row0 + myrow + rr) * P_DIM;
            out[orow + pA] = accA[rr] + boA;
            if (hasB) out[orow + pB] = accB[rr] + boB;
        }
    }
}

// -------- fp32 fallback — used only if ws_size is too small.
__global__ __launch_bounds__(256, 1)
void gru_fallback(const float* __restrict__ x,
                  const float* __restrict__ W_ih,
                  const float* __restrict__ Whh,
                  const float* __restrict__ b_ih,
                  const float* __restrict__ b_hh,
                  const float* __restrict__ Wout,
                  const float* __restrict__ b_out,
                  float* __restrict__ out) {
    __shared__ float hbuf[2][TB][H_DIM];

    const int tid   = threadIdx.x;
    const int cid   = tid & 63;
    const int rid   = tid >> 6;
    const int row0  = blockIdx.x * TB;
    const int myrow = rid * 8;
    const int c0    = cid * 4;

    float wih[3][4], bc[2][4], bihn[4], bhhn[4];
#pragma unroll
    for (int cc = 0; cc < 4; ++cc) {
        const int j = c0 + cc;
        wih[0][cc] = W_ih[j];
        wih[1][cc] = W_ih[H_DIM + j];
        wih[2][cc] = W_ih[2 * H_DIM + j];
        bc[0][cc]  = b_ih[j] + b_hh[j];
        bc[1][cc]  = b_ih[H_DIM + j] + b_hh[H_DIM + j];
        bihn[cc]   = b_ih[2 * H_DIM + j];
        bhhn[cc]   = b_hh[2 * H_DIM + j];
    }
    for (int i = tid; i < TB * H_DIM; i += 256) (&hbuf[0][0][0])[i] = 0.0f;
    float h_own[8][4];
#pragma unroll
    for (int rr = 0; rr < 8; ++rr)
#pragma unroll
        for (int cc = 0; cc < 4; ++cc) h_own[rr][cc] = 0.0f;
    __syncthreads();

    int p = 0;
    for (int t = 0; t < S_LEN; ++t) {
        float xv[8];
#pragma unroll
        for (int rr = 0; rr < 8; ++rr)
            xv[rr] = x[(size_t)(row0 + myrow + rr) * S_LEN + t];

        float acc[3][8][4];
#pragma unroll
        for (int rr = 0; rr < 8; ++rr)
#pragma unroll
            for (int cc = 0; cc < 4; ++cc) {
                acc[0][rr][cc] = fmaf(xv[rr], wih[0][cc], bc[0][cc]);
                acc[1][rr][cc] = fmaf(xv[rr], wih[1][cc], bc[1][cc]);
                acc[2][rr][cc] = bhhn[cc];
            }
        const float* hb = &hbuf[p][0][0];
        for (int k = 0; k < H_DIM; k += 4) {
            float4 hv[8];
#pragma unroll
            for (int rr = 0; rr < 8; ++rr)
                hv[rr] = *(const float4*)(hb + (myrow + rr) * H_DIM + k);
#pragma unroll
            for (int g = 0; g < 3; ++g)
#pragma unroll
                for (int kk = 0; kk < 4; ++kk) {
                    float wrow[4];
#pragma unroll
                    for (int cc = 0; cc < 4; ++cc)
                        wrow[cc] = Whh[(size_t)(g * H_DIM + c0 + cc) * H_DIM + k + kk];
#pragma unroll
                    for (int rr = 0; rr < 8; ++rr) {
                        const float hvv = (&hv[rr].x)[kk];
#pragma unroll
                        for (int cc = 0; cc < 4; ++cc)
                            acc[g][rr][cc] = fmaf(hvv, wrow[cc], acc[g][rr][cc]);
                    }
                }
        }
#pragma unroll
        for (int rr = 0; rr < 8; ++rr) {
            float4 hnew;
#pragma unroll
            for (int cc = 0; cc < 4; ++cc) {
                const float r_  = sigmoid_fast(acc[0][rr][cc]);
                const float z_  = sigmoid_fast(acc[1][rr][cc]);
                const float i_n = fmaf(xv[rr], wih[2][cc], bihn[cc]);
                const float n_  = tanh_fast(fmaf(r_, acc[2][rr][cc], i_n));
                const float hv2 = (1.0f - z_) * n_ + z_ * h_own[rr][cc];
                h_own[rr][cc] = hv2;
                (&hnew.x)[cc] = hv2;
            }
            *(float4*)&hbuf[1 - p][myrow + rr][c0] = hnew;
        }
        __syncthreads();
        p ^= 1;
    }

    const int  pA   = cid;
    const int  pB   = 64 + cid;
    const bool hasB = (cid < 32);
    float accA[8], accB[8];
#pragma unroll
    for (int rr = 0; rr < 8; ++rr) { accA[rr] = 0.0f; accB[rr] = 0.0f; }
    for (int k = 0; k < H_DIM; k += 4) {
        float4 hv[8];
#pragma unroll
        for (int rr = 0; rr < 8; ++rr)
            hv[rr] = *(const float4*)&hbuf[p][myrow + rr][k];
        float wA[4], wB[4];
#pragma unroll
        for (int kk = 0; kk < 4; ++kk) {
            wA[kk] = Wout[(size_t)pA * H_DIM + k + kk];
            wB[kk] = hasB ? Wout[(size_t)pB * H_DIM + k + kk] : 0.0f;
        }
#pragma unroll
        for (int kk = 0; kk < 4; ++kk)
#pragma unroll
            for (int rr = 0; rr < 8; ++rr) {
                const float hvv = (&hv[rr].x)[kk];
                accA[rr] = fmaf(hvv, wA[kk], accA[rr]);
                accB[rr] = fmaf(hvv, wB[kk], accB[rr]);
            }
    }
    const float boA = b_out[pA];
    const float boB = hasB ? b_out[pB] : 0.0f;
#pragma unroll
    for (int rr = 0; rr < 8; ++rr) {
        const size_t orow = (size_t)(row0 + myrow + rr) * P_DIM;
        out[orow + pA] = accA[rr] + boA;
        if (hasB) out[orow + pB] = accB[rr] + boB;
    }
}

extern "C" void kernel_launch(void* const* d_in, const int* in_sizes, int n_in,
                              void* d_out, int out_size, void* d_ws, size_t ws_size,
                              hipStream_t stream) {
    const float* x     = (const float*)d_in[0];
    const float* W_ih  = (const float*)d_in[1];
    const float* W_hh  = (const float*)d_in[2];
    const float* b_ih  = (const float*)d_in[3];
    const float* b_hh  = (const float*)d_in[4];
    const float* W_out = (const float*)d_in[5];
    const float* b_out = (const float*)d_in[6];
    float* out = (float*)d_out;

    const size_t bpack_elems = 8 * 48 * 64 * 8;          // 196608 bf16 per matrix
    const size_t wot_elems   = (size_t)H_DIM * P_DIM;    // 24576 fp32
    const size_t ctr_off = bpack_elems * 2 * sizeof(unsigned short) * 2 +
                           wot_elems * sizeof(float);    // 1671168 B (16-aligned)
    const size_t need = ctr_off + sizeof(unsigned int);

    if (ws_size >= need) {
        unsigned short* Bh = (unsigned short*)d_ws;
        unsigned short* Bl = Bh + bpack_elems * 2;
        float* WoT = (float*)(Bl + bpack_elems * 2);
        unsigned int* ctr = (unsigned int*)((char*)d_ws + ctr_off);
        pack_weights<<<G3, H_DIM, 0, stream>>>(W_hh, W_out, Bh, Bl, WoT, ctr);
        gru_mfma<<<B_ROWS / TB, 512, 0, stream>>>(x, W_ih, b_ih, b_hh,
                                                  Bh, Bl, WoT, b_out, out, ctr);
    } else {
        gru_fallback<<<B_ROWS / TB, 256, 0, stream>>>(x, W_ih, W_hh, b_ih, b_hh,
                                                      W_out, b_out, out);
    }
}

// Round 7
// 5849.665 us; speedup vs baseline: 2.3112x; 1.4660x over previous
//
#include <hip/hip_runtime.h>
#include <math.h>

// Problem constants
#define B_ROWS 8192
#define S_LEN  512
#define H_DIM  256
#define G3     768          // 3*H
#define P_DIM  96
#define TB     32           // batch rows per block

typedef __attribute__((ext_vector_type(8))) short short8;   // 8 bf16 (4 VGPRs)
typedef __attribute__((ext_vector_type(4))) float floatx4;  // MFMA C/D frag

__device__ __forceinline__ float sigmoid_fast(float v) {
    return 1.0f / (1.0f + __expf(-v));
}
__device__ __forceinline__ float tanh_fast(float v) {
    return 1.0f - 2.0f / (__expf(2.0f * v) + 1.0f);
}
__device__ __forceinline__ unsigned short f32_bf16_rtn(float f) {
    unsigned int u = __float_as_uint(f);
    u += 0x7fffu + ((u >> 16) & 1u);   // round-to-nearest-even
    return (unsigned short)(u >> 16);
}
__device__ __forceinline__ float bf16_f32(unsigned short h) {
    return __uint_as_float(((unsigned int)h) << 16);
}

// -------- One-time weight pack: W_hh -> per-lane MFMA B-fragments (hi/lo bf16).
// B[k][n] = W_hh[n][k].  16x16x32 B-frag: lane holds B[n=lane&15][k=quad*8+j].
// Tile index = (k>>5)*48 + (j>>4); lane = (j&15) | (((k>>3)&3)<<4); short = k&7.
// Also WoT[k][p] = W_out[p][k]; also zeroes the phase-sync counter.
__global__ void pack_weights(const float* __restrict__ W_hh,
                             const float* __restrict__ W_out,
                             unsigned short* __restrict__ Bh,
                             unsigned short* __restrict__ Bl,
                             float* __restrict__ WoT,
                             unsigned int* __restrict__ ctr) {
    const int j = blockIdx.x;    // gate col 0..767
    const int k = threadIdx.x;   // h idx   0..255
    const float wv = W_hh[j * H_DIM + k];
    const unsigned short hi = f32_bf16_rtn(wv);
    const unsigned short lo = f32_bf16_rtn(wv - bf16_f32(hi));
    const int idx = (((k >> 5) * 48 + (j >> 4)) * 64 +
                     ((j & 15) | (((k >> 3) & 3) << 4))) * 8 + (k & 7);
    Bh[idx] = hi;
    Bl[idx] = lo;
    if (j < P_DIM) WoT[k * P_DIM + j] = W_out[j * H_DIM + k];
    if (j == 0 && k == 0) *ctr = 0u;   // d_ws is re-poisoned every launch
}

// LDS layout (~148 KiB):
//   [0,       65536)  A-fragments, double-buffered: buf*32768 + (hi/lo)*16384
//                     + chunk(kc*2+mt)*1024 + slot*16 + short*2, slot = g(row),
//                     g(v) = v ^ ((v>>2)&7)  (reads conflict-free per 8-lane
//                     group, writes hit 8 distinct bank groups)
//   [65536,   69888)  xtile[2][32][17] fp32 (stride 17 kills bcast conflicts)
//   [69888,  151808)  W cache: 80 tiles x 1 KiB
//                     slots 0..47  = kc=6 lo  (index g*16 + w*2 + ht)
//                     slots 48..79 = kc=5 hi, g<2 (index g*16 + w*2 + ht)
#define A_OFF   0
#define X_OFF   65536
#define W_OFF   69888
#define LDS_SZ  151808
#define XSTR    17

union U16 { uint4 u; short8 s; };

__device__ __forceinline__ void mfma3(floatx4& c0, floatx4& c1,
                                      const short8& ah0, const short8& ah1,
                                      const short8& al0, const short8& al1,
                                      const short8& bh, const short8& bl) {
    c0 = __builtin_amdgcn_mfma_f32_16x16x32_bf16(ah0, bh, c0, 0, 0, 0);
    c1 = __builtin_amdgcn_mfma_f32_16x16x32_bf16(ah1, bh, c1, 0, 0, 0);
    c0 = __builtin_amdgcn_mfma_f32_16x16x32_bf16(al0, bh, c0, 0, 0, 0);
    c1 = __builtin_amdgcn_mfma_f32_16x16x32_bf16(al1, bh, c1, 0, 0, 0);
    c0 = __builtin_amdgcn_mfma_f32_16x16x32_bf16(ah0, bl, c0, 0, 0, 0);
    c1 = __builtin_amdgcn_mfma_f32_16x16x32_bf16(ah1, bl, c1, 0, 0, 0);
}

// Main persistent GRU kernel: split-bf16 MFMA + partial weight residency.
// K-loop is the R4-proven shape: per-kc transient loads (12 uint4 live max)
// immediately consumed — bounded register pressure, no spill. (R5/R6's deeper
// prefetch spilled to scratch -> multi-GB FETCH of spill reloads.)
// grid = 256 (1 block/CU, forced by LDS), block = 512 (8 waves, 2/SIMD).
__global__ __launch_bounds__(512, 2)
void gru_mfma(const float* __restrict__ x,
              const float* __restrict__ W_ih,
              const float* __restrict__ b_ih,
              const float* __restrict__ b_hh,
              const unsigned short* __restrict__ Bh,
              const unsigned short* __restrict__ Bl,
              const float* __restrict__ WoT,   // [256][96]
              const float* __restrict__ b_out,
              float* __restrict__ out,
              unsigned int* __restrict__ ctr) {
    __shared__ __align__(16) char smem[LDS_SZ];

    const int tid  = threadIdx.x;
    const int w    = tid >> 6;     // wave 0..7
    const int lane = tid & 63;
    const int q    = lane >> 4;    // quad
    const int c    = lane & 15;
    const int row0 = blockIdx.x * TB;

    const char* BhB = (const char*)Bh;
    const char* BlB = (const char*)Bl;

    // Per-thread gate params; col = 256*g + 32*w + 16*ht + c
    float wih[3][2], bcc[2][2], bihn[2], bhhn[2];
#pragma unroll
    for (int g = 0; g < 3; ++g)
#pragma unroll
        for (int ht = 0; ht < 2; ++ht) {
            const int col = g * H_DIM + w * 32 + ht * 16 + c;
            wih[g][ht] = W_ih[col];
            if (g < 2) {
                bcc[g][ht] = b_ih[col] + b_hh[col];
            } else {
                bihn[ht] = b_ih[col];
                bhhn[ht] = b_hh[col];
            }
        }

    // 32-bit per-lane tile offsets (gh = g*2 + ht); chunk kc adds kc*49152.
    unsigned int boff[6];
#pragma unroll
    for (int gh = 0; gh < 6; ++gh)
        boff[gh] = (unsigned)((((gh >> 1) * 16 + w * 2 + (gh & 1)) << 10) + (lane << 4));

    // Register-resident weight tiles: kc=7 hi+lo, kc=6 hi.  (72 VGPRs)
    short8 r7h[6], r7l[6], r6h[6];
#pragma unroll
    for (int gh = 0; gh < 6; ++gh) {
        U16 a, b, d;
        a.u = *(const uint4*)(BhB + (size_t)7 * 49152 + boff[gh]);
        b.u = *(const uint4*)(BlB + (size_t)7 * 49152 + boff[gh]);
        d.u = *(const uint4*)(BhB + (size_t)6 * 49152 + boff[gh]);
        r7h[gh] = a.s; r7l[gh] = b.s; r6h[gh] = d.s;
    }

    // LDS weight cache staging: 80 tiles (kc=6 lo: Bl tiles 288..335;
    // kc=5 hi g<2: Bh tiles 240..271).
    for (int i = tid; i < 80 * 64; i += 512) {
        const int slot = i >> 6, l16 = i & 63;
        const unsigned short* src = (slot < 48)
            ? (Bl + (size_t)(288 + slot) * 512 + l16 * 8)
            : (Bh + (size_t)(240 + slot - 48) * 512 + l16 * 8);
        *(uint4*)(smem + W_OFF + slot * 1024 + l16 * 16) = *(const uint4*)src;
    }

    // Zero both A-frag buffers (h0 = 0) and stage x for t=0..15.
    for (int i = tid; i < 16384; i += 512) ((int*)(smem + A_OFF))[i] = 0;
    float* xt = (float*)(smem + X_OFF);
    {
        const int r = tid >> 4, t2 = tid & 15;
        xt[r * XSTR + t2] = x[(size_t)(row0 + r) * S_LEN + t2];
    }
    __syncthreads();

    // h_old in C-frag layout: element (mt,ht,reg) = h[4q+reg+16mt][32w+16ht+c]
    float h_own[2][2][4];
#pragma unroll
    for (int mt = 0; mt < 2; ++mt)
#pragma unroll
        for (int ht = 0; ht < 2; ++ht)
#pragma unroll
            for (int r = 0; r < 4; ++r) h_own[mt][ht][r] = 0.0f;

    // Swizzle g(v) = v ^ ((v>>2)&7): reads conflict-free per aligned 8-lane
    // group; writer dest rows hit 8 distinct bank groups per store.
    const int rl16 = (lane ^ ((lane >> 2) & 7)) << 4;
    const int gxor = q + 4 * (c >> 3);       // == (d>>2)&7, thread-constant

    for (int t = 0; t < S_LEN; ++t) {
        const int cur = t & 1, nxt = cur ^ 1;
        const char* Ah = smem + A_OFF + cur * 32768;
        const char* Al = Ah + 16384;

        // x for my 8 rows (LDS broadcast, conflict-free via XSTR=17)
        float xr[2][4];
#pragma unroll
        for (int mt = 0; mt < 2; ++mt)
#pragma unroll
            for (int r = 0; r < 4; ++r)
                xr[mt][r] = xt[(((t >> 4) & 1) * 32 + q * 4 + r + 16 * mt) * XSTR + (t & 15)];

        // C frags [gate][mt][ht]; fold x-side pre-activation + bias into init.
        floatx4 acc[3][2][2];
#pragma unroll
        for (int mt = 0; mt < 2; ++mt)
#pragma unroll
            for (int ht = 0; ht < 2; ++ht)
#pragma unroll
                for (int r = 0; r < 4; ++r) {
                    acc[0][mt][ht][r] = fmaf(xr[mt][r], wih[0][ht], bcc[0][ht]);
                    acc[1][mt][ht][r] = fmaf(xr[mt][r], wih[1][ht], bcc[1][ht]);
                    acc[2][mt][ht][r] = bhhn[ht];
                }

        // ---- kc = 0..4: streamed from L2, R4 shape: 12 transient loads
        // per iteration, immediately consumed.  unroll 1 bounds pressure. ----
#pragma unroll 1
        for (int kc = 0; kc < 5; ++kc) {
            U16 bh[6], bl[6];
            {
                const size_t kb = (size_t)kc * 49152;
#pragma unroll
                for (int gh = 0; gh < 6; ++gh) {
                    bh[gh].u = *(const uint4*)(BhB + kb + boff[gh]);
                    bl[gh].u = *(const uint4*)(BlB + kb + boff[gh]);
                }
            }
            const int cb = (kc * 2) << 10;
            short8 ah0 = *(const short8*)(Ah + cb + rl16);
            short8 ah1 = *(const short8*)(Ah + cb + 1024 + rl16);
            short8 al0 = *(const short8*)(Al + cb + rl16);
            short8 al1 = *(const short8*)(Al + cb + 1024 + rl16);
#pragma unroll
            for (int gh = 0; gh < 6; ++gh)
                mfma3(acc[gh >> 1][0][gh & 1], acc[gh >> 1][1][gh & 1],
                      ah0, ah1, al0, al1, bh[gh].s, bl[gh].s);
        }

        // ---- kc = 5: hi g<2 from LDS cache, hi g=2 + all lo streamed ----
        {
            const int cb = 10 << 10;
            short8 ah0 = *(const short8*)(Ah + cb + rl16);
            short8 ah1 = *(const short8*)(Ah + cb + 1024 + rl16);
            short8 al0 = *(const short8*)(Al + cb + rl16);
            short8 al1 = *(const short8*)(Al + cb + 1024 + rl16);
            const size_t kb = (size_t)5 * 49152;
#pragma unroll
            for (int gh = 0; gh < 6; ++gh) {
                U16 bh, bl;
                if (gh < 4) {
                    const int slot = 48 + (gh >> 1) * 16 + w * 2 + (gh & 1);
                    bh.s = *(const short8*)(smem + W_OFF + slot * 1024 + lane * 16);
                } else {
                    bh.u = *(const uint4*)(BhB + kb + boff[gh]);
                }
                bl.u = *(const uint4*)(BlB + kb + boff[gh]);
                mfma3(acc[gh >> 1][0][gh & 1], acc[gh >> 1][1][gh & 1],
                      ah0, ah1, al0, al1, bh.s, bl.s);
            }
        }

        // ---- kc = 6: hi from regs, lo from LDS cache ----
        {
            const int cb = 12 << 10;
            short8 ah0 = *(const short8*)(Ah + cb + rl16);
            short8 ah1 = *(const short8*)(Ah + cb + 1024 + rl16);
            short8 al0 = *(const short8*)(Al + cb + rl16);
            short8 al1 = *(const short8*)(Al + cb + 1024 + rl16);
#pragma unroll
            for (int gh = 0; gh < 6; ++gh) {
                const int slot = (gh >> 1) * 16 + w * 2 + (gh & 1);
                short8 bl = *(const short8*)(smem + W_OFF + slot * 1024 + lane * 16);
                mfma3(acc[gh >> 1][0][gh & 1], acc[gh >> 1][1][gh & 1],
                      ah0, ah1, al0, al1, r6h[gh], bl);
            }
        }

        // ---- kc = 7: fully register-resident ----
        {
            const int cb = 14 << 10;
            short8 ah0 = *(const short8*)(Ah + cb + rl16);
            short8 ah1 = *(const short8*)(Ah + cb + 1024 + rl16);
            short8 al0 = *(const short8*)(Al + cb + rl16);
            short8 al1 = *(const short8*)(Al + cb + 1024 + rl16);
#pragma unroll
            for (int gh = 0; gh < 6; ++gh)
                mfma3(acc[gh >> 1][0][gh & 1], acc[gh >> 1][1][gh & 1],
                      ah0, ah1, al0, al1, r7h[gh], r7l[gh]);
        }

        // Gates + h update (in-register); scatter next A-frags (g-swizzled).
        char* Anx = smem + A_OFF + nxt * 32768;
#pragma unroll
        for (int mt = 0; mt < 2; ++mt) {
            char* chh = Anx + (w * 2 + mt) * 1024;          // hi chunk (kc=w)
            char* cll = chh + 16384;                        // lo chunk
#pragma unroll
            for (int ht = 0; ht < 2; ++ht)
#pragma unroll
                for (int r = 0; r < 4; ++r) {
                    const float rr  = sigmoid_fast(acc[0][mt][ht][r]);
                    const float zz  = sigmoid_fast(acc[1][mt][ht][r]);
                    const float inn = fmaf(xr[mt][r], wih[2][ht], bihn[ht]);
                    const float nn  = tanh_fast(fmaf(rr, acc[2][mt][ht][r], inn));
                    const float hv  = (1.0f - zz) * nn + zz * h_own[mt][ht][r];
                    h_own[mt][ht][r] = hv;
                    const unsigned short hi = f32_bf16_rtn(hv);
                    // lo truncated (error 2^-17-relative, invisible vs 2^-11)
                    const unsigned short lo =
                        (unsigned short)(__float_as_uint(hv - bf16_f32(hi)) >> 16);
                    const int d   = (q * 4 + r) | ((2 * ht + (c >> 3)) << 4);
                    const int off = ((d ^ gxor) << 4) + ((c & 7) << 1);
                    *(unsigned short*)(chh + off) = hi;
                    *(unsigned short*)(cll + off) = lo;
                }
        }

        // Re-stage x for the next 16 steps (into the idle x buffer).
        const bool tick = ((t & 15) == 15) && (t != S_LEN - 1);
        if (tick) {
            const int r = tid >> 4, t2 = tid & 15;
            xt[((((t + 1) >> 4) & 1) * 32 + r) * XSTR + t2] =
                x[(size_t)(row0 + r) * S_LEN + (t + 1) + t2];
        }
        __syncthreads();   // single barrier: next A-frags + x tile visible

        // Phase-alignment heartbeat every 16 steps (R4 params): keeps all 256
        // blocks' weight streams in phase so per-XCD L2 stays hot.  Pure
        // timing hint — bounded spin, no data dependency.
        if (tick) {
            if (tid == 0) {
                const unsigned int tgt = 256u * (unsigned)((t >> 4) + 1);
                atomicAdd(ctr, 1u);
                for (int spin = 0; spin < (1 << 17); ++spin) {
                    if (__hip_atomic_load(ctr, __ATOMIC_RELAXED,
                                          __HIP_MEMORY_SCOPE_AGENT) >= tgt) break;
                    __builtin_amdgcn_s_sleep(4);
                }
            }
            __syncthreads();
        }
    }

    // -------- Epilogue: dump final h (fp32, from registers) and project.
    float* hfin = (float*)(smem);   // reuse A region: [32][256]
#pragma unroll
    for (int mt = 0; mt < 2; ++mt)
#pragma unroll
        for (int ht = 0; ht < 2; ++ht)
#pragma unroll
            for (int r = 0; r < 4; ++r) {
                const int m = q * 4 + r + 16 * mt;
                const int k = w * 32 + ht * 16 + c;
                hfin[m * H_DIM + k] = h_own[mt][ht][r];
            }
    __syncthreads();

    if (tid < 256) {
        const int cid   = tid & 63;
        const int rid   = tid >> 6;
        const int myrow = rid * 8;
        const int pA    = cid;
        const int pB    = 64 + cid;
        const bool hasB = (cid < 32);
        float accA[8], accB[8];
#pragma unroll
        for (int rr = 0; rr < 8; ++rr) { accA[rr] = 0.0f; accB[rr] = 0.0f; }

        for (int k = 0; k < H_DIM; k += 4) {
            float4 hv[8];
#pragma unroll
            for (int rr = 0; rr < 8; ++rr)
                hv[rr] = *(const float4*)&hfin[(myrow + rr) * H_DIM + k];
            float wA[4], wB[4];
#pragma unroll
            for (int kk = 0; kk < 4; ++kk) {
                wA[kk] = WoT[(size_t)(k + kk) * P_DIM + pA];
                wB[kk] = hasB ? WoT[(size_t)(k + kk) * P_DIM + pB] : 0.0f;
            }
#pragma unroll
            for (int kk = 0; kk < 4; ++kk)
#pragma unroll
                for (int rr = 0; rr < 8; ++rr) {
                    const float hvv = (&hv[rr].x)[kk];
                    accA[rr] = fmaf(hvv, wA[kk], accA[rr]);
                    accB[rr] = fmaf(hvv, wB[kk], accB[rr]);
                }
        }
        const float boA = b_out[pA];
        const float boB = hasB ? b_out[pB] : 0.0f;
#pragma unroll
        for (int rr = 0; rr < 8; ++rr) {
            const size_t orow = (size_t)(row0 + myrow + rr) * P_DIM;
            out[orow + pA] = accA[rr] + boA;
            if (hasB) out[orow + pB] = accB[rr] + boB;
        }
    }
}

// -------- fp32 fallback — used only if ws_size is too small.
__global__ __launch_bounds__(256, 1)
void gru_fallback(const float* __restrict__ x,
                  const float* __restrict__ W_ih,
                  const float* __restrict__ Whh,
                  const float* __restrict__ b_ih,
                  const float* __restrict__ b_hh,
                  const float* __restrict__ Wout,
                  const float* __restrict__ b_out,
                  float* __restrict__ out) {
    __shared__ float hbuf[2][TB][H_DIM];

    const int tid   = threadIdx.x;
    const int cid   = tid & 63;
    const int rid   = tid >> 6;
    const int row0  = blockIdx.x * TB;
    const int myrow = rid * 8;
    const int c0    = cid * 4;

    float wih[3][4], bc[2][4], bihn[4], bhhn[4];
#pragma unroll
    for (int cc = 0; cc < 4; ++cc) {
        const int j = c0 + cc;
        wih[0][cc] = W_ih[j];
        wih[1][cc] = W_ih[H_DIM + j];
        wih[2][cc] = W_ih[2 * H_DIM + j];
        bc[0][cc]  = b_ih[j] + b_hh[j];
        bc[1][cc]  = b_ih[H_DIM + j] + b_hh[H_DIM + j];
        bihn[cc]   = b_ih[2 * H_DIM + j];
        bhhn[cc]   = b_hh[2 * H_DIM + j];
    }
    for (int i = tid; i < TB * H_DIM; i += 256) (&hbuf[0][0][0])[i] = 0.0f;
    float h_own[8][4];
#pragma unroll
    for (int rr = 0; rr < 8; ++rr)
#pragma unroll
        for (int cc = 0; cc < 4; ++cc) h_own[rr][cc] = 0.0f;
    __syncthreads();

    int p = 0;
    for (int t = 0; t < S_LEN; ++t) {
        float xv[8];
#pragma unroll
        for (int rr = 0; rr < 8; ++rr)
            xv[rr] = x[(size_t)(row0 + myrow + rr) * S_LEN + t];

        float acc[3][8][4];
#pragma unroll
        for (int rr = 0; rr < 8; ++rr)
#pragma unroll
            for (int cc = 0; cc < 4; ++cc) {
                acc[0][rr][cc] = fmaf(xv[rr], wih[0][cc], bc[0][cc]);
                acc[1][rr][cc] = fmaf(xv[rr], wih[1][cc], bc[1][cc]);
                acc[2][rr][cc] = bhhn[cc];
            }
        const float* hb = &hbuf[p][0][0];
        for (int k = 0; k < H_DIM; k += 4) {
            float4 hv[8];
#pragma unroll
            for (int rr = 0; rr < 8; ++rr)
                hv[rr] = *(const float4*)(hb + (myrow + rr) * H_DIM + k);
#pragma unroll
            for (int g = 0; g < 3; ++g)
#pragma unroll
                for (int kk = 0; kk < 4; ++kk) {
                    float wrow[4];
#pragma unroll
                    for (int cc = 0; cc < 4; ++cc)
                        wrow[cc] = Whh[(size_t)(g * H_DIM + c0 + cc) * H_DIM + k + kk];
#pragma unroll
                    for (int rr = 0; rr < 8; ++rr) {
                        const float hvv = (&hv[rr].x)[kk];
#pragma unroll
                        for (int cc = 0; cc < 4; ++cc)
                            acc[g][rr][cc] = fmaf(hvv, wrow[cc], acc[g][rr][cc]);
                    }
                }
        }
#pragma unroll
        for (int rr = 0; rr < 8; ++rr) {
            float4 hnew;
#pragma unroll
            for (int cc = 0; cc < 4; ++cc) {
                const float r_  = sigmoid_fast(acc[0][rr][cc]);
                const float z_  = sigmoid_fast(acc[1][rr][cc]);
                const float i_n = fmaf(xv[rr], wih[2][cc], bihn[cc]);
                const float n_  = tanh_fast(fmaf(r_, acc[2][rr][cc], i_n));
                const float hv2 = (1.0f - z_) * n_ + z_ * h_own[rr][cc];
                h_own[rr][cc] = hv2;
                (&hnew.x)[cc] = hv2;
            }
            *(float4*)&hbuf[1 - p][myrow + rr][c0] = hnew;
        }
        __syncthreads();
        p ^= 1;
    }

    const int  pA   = cid;
    const int  pB   = 64 + cid;
    const bool hasB = (cid < 32);
    float accA[8], accB[8];
#pragma unroll
    for (int rr = 0; rr < 8; ++rr) { accA[rr] = 0.0f; accB[rr] = 0.0f; }
    for (int k = 0; k < H_DIM; k += 4) {
        float4 hv[8];
#pragma unroll
        for (int rr = 0; rr < 8; ++rr)
            hv[rr] = *(const float4*)&hbuf[p][myrow + rr][k];
        float wA[4], wB[4];
#pragma unroll
        for (int kk = 0; kk < 4; ++kk) {
            wA[kk] = Wout[(size_t)pA * H_DIM + k + kk];
            wB[kk] = hasB ? Wout[(size_t)pB * H_DIM + k + kk] : 0.0f;
        }
#pragma unroll
        for (int kk = 0; kk < 4; ++kk)
#pragma unroll
            for (int rr = 0; rr < 8; ++rr) {
                const float hvv = (&hv[rr].x)[kk];
                accA[rr] = fmaf(hvv, wA[kk], accA[rr]);
                accB[rr] = fmaf(hvv, wB[kk], accB[rr]);
            }
    }
    const float boA = b_out[pA];
    const float boB = hasB ? b_out[pB] : 0.0f;
#pragma unroll
    for (int rr = 0; rr < 8; ++rr) {
        const size_t orow = (size_t)(row0 + myrow + rr) * P_DIM;
        out[orow + pA] = accA[rr] + boA;
        if (hasB) out[orow + pB] = accB[rr] + boB;
    }
}

extern "C" void kernel_launch(void* const* d_in, const int* in_sizes, int n_in,
                              void* d_out, int out_size, void* d_ws, size_t ws_size,
                              hipStream_t stream) {
    const float* x     = (const float*)d_in[0];
    const float* W_ih  = (const float*)d_in[1];
    const float* W_hh  = (const float*)d_in[2];
    const float* b_ih  = (const float*)d_in[3];
    const float* b_hh  = (const float*)d_in[4];
    const float* W_out = (const float*)d_in[5];
    const float* b_out = (const float*)d_in[6];
    float* out = (float*)d_out;

    const size_t bpack_elems = 8 * 48 * 64 * 8;          // 196608 bf16 per matrix
    const size_t wot_elems   = (size_t)H_DIM * P_DIM;    // 24576 fp32
    const size_t ctr_off = bpack_elems * 2 * sizeof(unsigned short) * 2 +
                           wot_elems * sizeof(float);    // 1671168 B (16-aligned)
    const size_t need = ctr_off + sizeof(unsigned int);

    if (ws_size >= need) {
        unsigned short* Bh = (unsigned short*)d_ws;
        unsigned short* Bl = Bh + bpack_elems * 2;
        float* WoT = (float*)(Bl + bpack_elems * 2);
        unsigned int* ctr = (unsigned int*)((char*)d_ws + ctr_off);
        pack_weights<<<G3, H_DIM, 0, stream>>>(W_hh, W_out, Bh, Bl, WoT, ctr);
        gru_mfma<<<B_ROWS / TB, 512, 0, stream>>>(x, W_ih, b_ih, b_hh,
                                                  Bh, Bl, WoT, b_out, out, ctr);
    } else {
        gru_fallback<<<B_ROWS / TB, 256, 0, stream>>>(x, W_ih, W_hh, b_ih, b_hh,
                                                      W_out, b_out, out);
    }
}